// Round 1
// baseline (11.003 us; speedup 1.0000x reference)
//
#include <hip/hip_runtime.h>

// SpatialAttentionLayer collapses algebraically because V = ones(B,L,O,d):
//  - X1 = V@W1+b1 is constant along the row index i
//  - => net[b,l,i,j] is constant in i => softmax over axis=-2 (i) is exactly 1/O
//  - => phi = psi = theta = 1/256 everywhere, independent of X
//  - V_ = V@W+b = c[d] := colsum(W)[d] + b[d], constant across (b,l,i)
//  - out = V_ + (3/O * ones) @ V_ = 4 * c[d], broadcast to (B,L,O,d)
// Kernel: compute 64 constants from W (64x64) and b (64), broadcast-write
// 4,194,304 f32 (16.8 MB). Pure write-BW bound.

__global__ __launch_bounds__(256) void spa_const_broadcast(
    const float* __restrict__ W,   // (64,64) row-major: W[k*64 + d]
    const float* __restrict__ b,   // (64,)
    float4* __restrict__ out,      // out_size/4 float4s
    int total4) {
    __shared__ float c[64];
    const int t = threadIdx.x;
    if (t < 64) {
        float s = 0.0f;
        #pragma unroll
        for (int k = 0; k < 64; ++k) s += W[k * 64 + t];
        c[t] = 4.0f * (s + b[t]);
    }
    __syncthreads();

    // Each float4 at flat index idx covers floats [idx*4, idx*4+4) of a
    // pattern with period 64 floats (16 float4s). Grid stride (gridDim*256)
    // is a multiple of 16, so each thread's offset within the period is
    // fixed -> hoist the constant vector out of the loop.
    const int off = (t & 15) * 4;
    const float4 v = make_float4(c[off], c[off + 1], c[off + 2], c[off + 3]);

    const int stride = gridDim.x * blockDim.x;
    for (int idx = blockIdx.x * blockDim.x + t; idx < total4; idx += stride) {
        out[idx] = v;
    }
}

extern "C" void kernel_launch(void* const* d_in, const int* in_sizes, int n_in,
                              void* d_out, int out_size, void* d_ws, size_t ws_size,
                              hipStream_t stream) {
    // inputs: 0:X 1:W1 2:b1 3:w2 4:b2 5:W 6:b   (only W, b matter)
    const float* W = (const float*)d_in[5];
    const float* b = (const float*)d_in[6];
    float* out = (float*)d_out;

    const int total4 = out_size / 4;  // 4,194,304 / 4 = 1,048,576
    const int threads = 256;
    // 2048 blocks -> 524,288 threads, 2 float4 stores each. Caps grid per
    // Guideline 11 for memory-bound ops.
    const int blocks = 2048;
    spa_const_broadcast<<<blocks, threads, 0, stream>>>(
        W, b, (float4*)out, total4);
}